// Round 1
// baseline (531.326 us; speedup 1.0000x reference)
//
#include <hip/hip_runtime.h>
#include <hip/hip_bf16.h>
#include <math.h>

#define B_ 64
#define IN_ 256
#define H_ 512
#define M_ 64
#define N_ 8192
#define G4_ 2048   // 4*H

// ---------------- workspace layout (float offsets) ----------------
#define OFF_SCORE  0          // B*N = 524288
#define OFF_GATES  524288     // B*4H = 131072
#define OFF_RK     655360     // 4096
#define OFF_WK     659456     // 4096
#define OFF_WA     663552     // B*128 = 8192 (e|a, e already sigmoided)
#define OFF_MREAD  671744     // 4096
#define OFF_RBETA  675840
#define OFF_RG     675904
#define OFF_RGAMMA 675968
#define OFF_RNK    676032
#define OFF_RS     676096     // 192
#define OFF_WBETA  676352
#define OFF_WG     676416
#define OFF_WGAMMA 676480
#define OFF_WNK    676544
#define OFF_WS     676608     // 192
// end ~ 676800 floats = 2.7 MB

__device__ __forceinline__ float sigf(float x) { return 1.0f / (1.0f + expf(-x)); }

// ---------------- controller: k, beta, g, gamma, s (+ write_all) ----------------
__global__ __launch_bounds__(256) void controller_kernel(
    const float* __restrict__ hsrc,
    const float* __restrict__ kw, const float* __restrict__ kb,
    const float* __restrict__ cw, const float* __restrict__ cb,
    const float* __restrict__ sw, const float* __restrict__ sb,
    const float* __restrict__ ww, const float* __restrict__ wb,
    float* __restrict__ k_out, float* __restrict__ beta_o,
    float* __restrict__ g_o, float* __restrict__ gamma_o,
    float* __restrict__ nk_o, float* __restrict__ s_o,
    float* __restrict__ wa_o)
{
    int b = blockIdx.x;
    __shared__ float hs[H_];
    __shared__ float tmp[6];
    __shared__ float kvals[M_];
    for (int i = threadIdx.x; i < H_; i += 256) hs[i] = hsrc[b * H_ + i];
    __syncthreads();
    int nout = wa_o ? 198 : 70;
    for (int o = threadIdx.x; o < nout; o += 256) {
        const float* wrow; float bias;
        if (o < 64)      { wrow = kw + o * H_;        bias = kb[o]; }
        else if (o < 67) { wrow = cw + (o - 64) * H_; bias = cb[o - 64]; }
        else if (o < 70) { wrow = sw + (o - 67) * H_; bias = sb[o - 67]; }
        else             { wrow = ww + (o - 70) * H_; bias = wb[o - 70]; }
        float acc = bias;
        #pragma unroll 4
        for (int k = 0; k < H_; ++k) acc += hs[k] * wrow[k];
        if (o < 64) {
            float kv = tanhf(acc);
            kvals[o] = kv;
            k_out[b * M_ + o] = kv;
        } else if (o < 70) {
            tmp[o - 64] = acc;
        } else {
            int j = o - 70;
            wa_o[b * 128 + j] = (j < 64) ? sigf(acc) : acc;  // e sigmoided, a raw
        }
    }
    __syncthreads();
    if (threadIdx.x == 0) {
        beta_o[b]  = fmaxf(tmp[0], 0.0f) + 1e-4f;
        g_o[b]     = sigf(tmp[1]);
        gamma_o[b] = fmaxf(tmp[2], 0.0f) + 1.0001f;
        float s0 = tmp[3], s1 = tmp[4], s2 = tmp[5];
        float mx = fmaxf(s0, fmaxf(s1, s2));
        float e0 = expf(s0 - mx), e1 = expf(s1 - mx), e2 = expf(s2 - mx);
        float ss = e0 + e1 + e2;
        s_o[b * 3 + 0] = e0 / ss; s_o[b * 3 + 1] = e1 / ss; s_o[b * 3 + 2] = e2 / ss;
        float nk = 0.0f;
        for (int m = 0; m < M_; ++m) nk += kvals[m] * kvals[m];
        nk_o[b] = nk;
    }
}

// ---------------- score pass: score[b,n] = beta * (k . M_bn) / (|M_bn|^2 * |k|^2) ----------------
// grid (32, B), block 256. 16 lanes cooperate per memory row (fully coalesced float4).
__global__ __launch_bounds__(256) void score_kernel(
    const float* __restrict__ mem, const float* __restrict__ kvec,
    const float* __restrict__ beta, const float* __restrict__ nk,
    float* __restrict__ score)
{
    int b = blockIdx.y;
    int lane = threadIdx.x & 63, wave = threadIdx.x >> 6;
    int mq = lane & 15, sub = lane >> 4;
    float4 k4 = ((const float4*)(kvec + b * M_))[mq];
    float be = beta[b], nkk = nk[b];
    const int chunk = N_ / 32;
    int base = blockIdx.x * chunk;
    const float4* memb = (const float4*)(mem + (size_t)b * N_ * M_);
    for (int it = 0; it < chunk / 16; ++it) {
        int n = base + it * 16 + wave * 4 + sub;
        float4 v = memb[(size_t)n * 16 + mq];
        float d  = v.x * k4.x + v.y * k4.y + v.z * k4.z + v.w * k4.w;
        float nm = v.x * v.x + v.y * v.y + v.z * v.z + v.w * v.w;
        #pragma unroll
        for (int off = 1; off < 16; off <<= 1) {
            d  += __shfl_xor(d, off);
            nm += __shfl_xor(nm, off);
        }
        if (mq == 0) score[(size_t)b * N_ + n] = be * d / (nm * nkk);
    }
}

// ---------------- address: softmax -> interpolate -> shift -> sharpen -> normalize ----------------
__global__ __launch_bounds__(1024) void address_kernel(
    const float* __restrict__ score, const float* __restrict__ head_tm1,
    const float* __restrict__ g_, const float* __restrict__ gamma_,
    const float* __restrict__ s_, float* __restrict__ head_out)
{
    int b = blockIdx.x;
    __shared__ float inter[N_];
    __shared__ float red[16];
    int tid = threadIdx.x;
    const float* sc = score + (size_t)b * N_;

    float v[8];
    float mx = -1e30f;
    #pragma unroll
    for (int r = 0; r < 8; ++r) { v[r] = sc[tid + r * 1024]; mx = fmaxf(mx, v[r]); }
    #pragma unroll
    for (int off = 32; off; off >>= 1) mx = fmaxf(mx, __shfl_xor(mx, off));
    if ((tid & 63) == 0) red[tid >> 6] = mx;
    __syncthreads();
    mx = red[0];
    for (int i = 1; i < 16; ++i) mx = fmaxf(mx, red[i]);
    __syncthreads();

    float sum = 0.0f;
    #pragma unroll
    for (int r = 0; r < 8; ++r) { v[r] = expf(v[r] - mx); sum += v[r]; }
    #pragma unroll
    for (int off = 32; off; off >>= 1) sum += __shfl_xor(sum, off);
    if ((tid & 63) == 0) red[tid >> 6] = sum;
    __syncthreads();
    sum = 0.0f;
    for (int i = 0; i < 16; ++i) sum += red[i];
    float inv = 1.0f / sum;
    __syncthreads();

    float gb = g_[b], gm = gamma_[b];
    float s0 = s_[b * 3], s1 = s_[b * 3 + 1], s2 = s_[b * 3 + 2];
    const float* ht = head_tm1 + (size_t)b * N_;
    #pragma unroll
    for (int r = 0; r < 8; ++r) {
        int n = tid + r * 1024;
        inter[n] = gb * (v[r] * inv) + (1.0f - gb) * ht[n];
    }
    __syncthreads();

    float outv[8];
    float psum = 0.0f;
    #pragma unroll
    for (int r = 0; r < 8; ++r) {
        int n = tid + r * 1024;
        float o = s0 * inter[(n + N_ - 2) & (N_ - 1)]
                + s1 * inter[(n + N_ - 1) & (N_ - 1)]
                + s2 * inter[n];
        o = powf(fmaxf(o, 0.0f), gm);
        outv[r] = o;
        psum += o;
    }
    #pragma unroll
    for (int off = 32; off; off >>= 1) psum += __shfl_xor(psum, off);
    if ((tid & 63) == 0) red[tid >> 6] = psum;
    __syncthreads();
    psum = 0.0f;
    for (int i = 0; i < 16; ++i) psum += red[i];
    float inv2 = 1.0f / psum;
    float* ho = head_out + (size_t)b * N_;
    #pragma unroll
    for (int r = 0; r < 8; ++r) ho[tid + r * 1024] = outv[r] * inv2;
}

// ---------------- M_read[b,m] = sum_n r_head[b,n] * Mem[b,n,m] ----------------
// grid (32, B), block 256. Requires mread zeroed beforehand.
__global__ __launch_bounds__(256) void mread_kernel(
    const float* __restrict__ mem, const float* __restrict__ rhead,
    float* __restrict__ mread)
{
    int b = blockIdx.y;
    int lane = threadIdx.x & 63, wave = threadIdx.x >> 6;
    int mq = lane & 15, sub = lane >> 4;
    const int chunk = N_ / 32;
    int base = blockIdx.x * chunk;
    const float4* memb = (const float4*)(mem + (size_t)b * N_ * M_);
    const float* rh = rhead + (size_t)b * N_;
    float4 acc = make_float4(0.f, 0.f, 0.f, 0.f);
    for (int it = 0; it < chunk / 16; ++it) {
        int n = base + it * 16 + wave * 4 + sub;
        float w = rh[n];
        float4 v = memb[(size_t)n * 16 + mq];
        acc.x += w * v.x; acc.y += w * v.y; acc.z += w * v.z; acc.w += w * v.w;
    }
    #pragma unroll
    for (int off = 16; off < 64; off <<= 1) {
        acc.x += __shfl_xor(acc.x, off); acc.y += __shfl_xor(acc.y, off);
        acc.z += __shfl_xor(acc.z, off); acc.w += __shfl_xor(acc.w, off);
    }
    __shared__ float4 wsum[4][16];
    if (sub == 0) wsum[wave][mq] = acc;
    __syncthreads();
    if (threadIdx.x < 16) {
        float4 t = wsum[0][threadIdx.x];
        for (int w2 = 1; w2 < 4; ++w2) {
            float4 u = wsum[w2][threadIdx.x];
            t.x += u.x; t.y += u.y; t.z += u.z; t.w += u.w;
        }
        float* dst = mread + b * M_ + threadIdx.x * 4;
        atomicAdd(dst + 0, t.x); atomicAdd(dst + 1, t.y);
        atomicAdd(dst + 2, t.z); atomicAdd(dst + 3, t.w);
    }
}

// ---------------- gates = [inp|M_read] @ W_ih^T + b_ih + h @ W_hh^T + b_hh ----------------
// grid 64 blocks (32 j each), block 256 = 64 b x 4 j-groups x 8 j.
__global__ __launch_bounds__(256) void gates_kernel(
    const float* __restrict__ inp, const float* __restrict__ mread,
    const float* __restrict__ h, const float* __restrict__ Wih,
    const float* __restrict__ bih, const float* __restrict__ Whh,
    const float* __restrict__ bhh, float* __restrict__ gates)
{
    int jb = blockIdx.x * 32;
    int tid = threadIdx.x;
    int bb = tid & 63;
    int jg = tid >> 6;
    __shared__ float Xs[64][65];
    __shared__ float Ws[32][65];
    float acc[8] = {0.f, 0.f, 0.f, 0.f, 0.f, 0.f, 0.f, 0.f};

    // part 1: W_ih, K = 320
    for (int kb = 0; kb < 320; kb += 64) {
        for (int i = tid; i < 64 * 64; i += 256) {
            int bl = i >> 6, kk = i & 63, k = kb + kk;
            Xs[bl][kk] = (k < IN_) ? inp[bl * IN_ + k] : mread[bl * M_ + (k - IN_)];
        }
        for (int i = tid; i < 32 * 64; i += 256) {
            int jj = i >> 6, kk = i & 63;
            Ws[jj][kk] = Wih[(size_t)(jb + jj) * 320 + kb + kk];
        }
        __syncthreads();
        for (int kk = 0; kk < 64; ++kk) {
            float xv = Xs[bb][kk];
            #pragma unroll
            for (int u = 0; u < 8; ++u) acc[u] += xv * Ws[jg * 8 + u][kk];
        }
        __syncthreads();
    }
    // part 2: W_hh, K = 512
    for (int kb = 0; kb < 512; kb += 64) {
        for (int i = tid; i < 64 * 64; i += 256) {
            int bl = i >> 6, kk = i & 63;
            Xs[bl][kk] = h[bl * H_ + kb + kk];
        }
        for (int i = tid; i < 32 * 64; i += 256) {
            int jj = i >> 6, kk = i & 63;
            Ws[jj][kk] = Whh[(size_t)(jb + jj) * 512 + kb + kk];
        }
        __syncthreads();
        for (int kk = 0; kk < 64; ++kk) {
            float xv = Xs[bb][kk];
            #pragma unroll
            for (int u = 0; u < 8; ++u) acc[u] += xv * Ws[jg * 8 + u][kk];
        }
        __syncthreads();
    }
    #pragma unroll
    for (int u = 0; u < 8; ++u) {
        int j = jb + jg * 8 + u;
        gates[bb * G4_ + j] = acc[u] + bih[j] + bhh[j];
    }
}

// ---------------- LSTM pointwise ----------------
__global__ __launch_bounds__(256) void lstm_kernel(
    const float* __restrict__ gates, const float* __restrict__ c_in,
    float* __restrict__ h_new, float* __restrict__ c_new)
{
    int i = blockIdx.x * 256 + threadIdx.x;
    if (i >= B_ * H_) return;
    int b = i >> 9, hh = i & 511;
    const float* gb = gates + b * G4_;
    float ig = gb[hh], fg = gb[H_ + hh], gg = gb[2 * H_ + hh], og = gb[3 * H_ + hh];
    float cn = sigf(fg) * c_in[i] + sigf(ig) * tanhf(gg);
    float hn = sigf(og) * tanhf(cn);
    c_new[i] = cn;
    h_new[i] = hn;
}

// ---------------- M_out = mem * (1 - w*e) + w*a ----------------
__global__ __launch_bounds__(256) void writemem_kernel(
    const float* __restrict__ mem, const float* __restrict__ whead,
    const float* __restrict__ wa, float* __restrict__ mout)
{
    size_t i4 = (size_t)blockIdx.x * 256 + threadIdx.x;  // float4 index
    int mq = (int)(i4 & 15);
    int n  = (int)((i4 >> 4) & (N_ - 1));
    int b  = (int)(i4 >> 17);
    float w = whead[(size_t)b * N_ + n];
    float4 e4 = ((const float4*)(wa + b * 128))[mq];
    float4 a4 = ((const float4*)(wa + b * 128 + 64))[mq];
    float4 v = ((const float4*)mem)[i4];
    float4 o;
    o.x = v.x * (1.0f - w * e4.x) + w * a4.x;
    o.y = v.y * (1.0f - w * e4.y) + w * a4.y;
    o.z = v.z * (1.0f - w * e4.z) + w * a4.z;
    o.w = v.w * (1.0f - w * e4.w) + w * a4.w;
    ((float4*)mout)[i4] = o;
}

// ---------------- launch ----------------
extern "C" void kernel_launch(void* const* d_in, const int* in_sizes, int n_in,
                              void* d_out, int out_size, void* d_ws, size_t ws_size,
                              hipStream_t stream) {
    (void)in_sizes; (void)n_in; (void)out_size; (void)ws_size;
    const float* inp     = (const float*)d_in[0];
    const float* h       = (const float*)d_in[1];
    const float* c       = (const float*)d_in[2];
    const float* rhead0  = (const float*)d_in[3];
    const float* whead0  = (const float*)d_in[4];
    const float* mem     = (const float*)d_in[5];
    const float* W_ih    = (const float*)d_in[6];
    const float* b_ih    = (const float*)d_in[7];
    const float* W_hh    = (const float*)d_in[8];
    const float* b_hh    = (const float*)d_in[9];
    const float* rk_w    = (const float*)d_in[10];
    const float* rk_b    = (const float*)d_in[11];
    const float* rc_w    = (const float*)d_in[12];
    const float* rc_b    = (const float*)d_in[13];
    const float* rs_w    = (const float*)d_in[14];
    const float* rs_b    = (const float*)d_in[15];
    const float* wk_w    = (const float*)d_in[16];
    const float* wk_b    = (const float*)d_in[17];
    const float* wc_w    = (const float*)d_in[18];
    const float* wc_b    = (const float*)d_in[19];
    const float* ws_w    = (const float*)d_in[20];
    const float* ws_b    = (const float*)d_in[21];
    const float* w_w     = (const float*)d_in[22];
    const float* w_b     = (const float*)d_in[23];

    float* ws = (float*)d_ws;
    float* out = (float*)d_out;
    float* h_new  = out;                       // 32768
    float* c_new  = out + 32768;               // 32768
    float* r_head = out + 65536;               // 524288
    float* w_head = out + 65536 + 524288;      // 524288
    float* m_out  = out + 65536 + 2 * 524288;  // 33554432

    // zero the M_read accumulator
    hipMemsetAsync(ws + OFF_MREAD, 0, M_ * B_ * sizeof(float) / 64 * 64, stream);

    // ---- read phase ----
    controller_kernel<<<B_, 256, 0, stream>>>(
        h, rk_w, rk_b, rc_w, rc_b, rs_w, rs_b, nullptr, nullptr,
        ws + OFF_RK, ws + OFF_RBETA, ws + OFF_RG, ws + OFF_RGAMMA,
        ws + OFF_RNK, ws + OFF_RS, nullptr);
    score_kernel<<<dim3(32, B_), 256, 0, stream>>>(
        mem, ws + OFF_RK, ws + OFF_RBETA, ws + OFF_RNK, ws + OFF_SCORE);
    address_kernel<<<B_, 1024, 0, stream>>>(
        ws + OFF_SCORE, rhead0, ws + OFF_RG, ws + OFF_RGAMMA, ws + OFF_RS, r_head);
    mread_kernel<<<dim3(32, B_), 256, 0, stream>>>(mem, r_head, ws + OFF_MREAD);

    // ---- LSTM ----
    gates_kernel<<<G4_ / 32, 256, 0, stream>>>(
        inp, ws + OFF_MREAD, h, W_ih, b_ih, W_hh, b_hh, ws + OFF_GATES);
    lstm_kernel<<<(B_ * H_ + 255) / 256, 256, 0, stream>>>(
        ws + OFF_GATES, c, h_new, c_new);

    // ---- write phase ----
    controller_kernel<<<B_, 256, 0, stream>>>(
        h_new, wk_w, wk_b, wc_w, wc_b, ws_w, ws_b, w_w, w_b,
        ws + OFF_WK, ws + OFF_WBETA, ws + OFF_WG, ws + OFF_WGAMMA,
        ws + OFF_WNK, ws + OFF_WS, ws + OFF_WA);
    score_kernel<<<dim3(32, B_), 256, 0, stream>>>(
        mem, ws + OFF_WK, ws + OFF_WBETA, ws + OFF_WNK, ws + OFF_SCORE);
    address_kernel<<<B_, 1024, 0, stream>>>(
        ws + OFF_SCORE, whead0, ws + OFF_WG, ws + OFF_WGAMMA, ws + OFF_WS, w_head);
    writemem_kernel<<<(B_ * N_ * M_ / 4) / 256, 256, 0, stream>>>(
        mem, w_head, ws + OFF_WA, m_out);
}

// Round 6
// 504.700 us; speedup vs baseline: 1.0528x; 1.0528x over previous
//
#include <hip/hip_runtime.h>
#include <hip/hip_bf16.h>
#include <math.h>

#define B_ 64
#define IN_ 256
#define H_ 512
#define M_ 64
#define N_ 8192
#define G4_ 2048   // 4*H

// ---------------- workspace layout (float offsets) ----------------
#define OFF_SCORE  0          // B*N = 524288
#define OFF_GATES  524288     // B*4H = 131072
#define OFF_RK     655360     // 4096
#define OFF_WK     659456     // 4096
#define OFF_WA     663552     // B*128 = 8192 (e|a, e already sigmoided)
// ---- zeroed region (one memset covers MREAD..WNK) ----
#define OFF_MREAD  671744     // 4096
#define OFF_RNK    675840     // 64
#define OFF_WNK    675904     // 64
#define ZERO_FLTS  4224
// ---- scalars ----
#define OFF_RBETA  675968
#define OFF_RG     676032
#define OFF_RGAMMA 676096
#define OFF_RS     676160     // 192 (raw logits)
#define OFF_WBETA  676352
#define OFF_WG     676416
#define OFF_WGAMMA 676480
#define OFF_WS     676544     // 192 (raw logits)
// end ~ 676736 floats = 2.7 MB

__device__ __forceinline__ float sigf(float x) { return 1.0f / (1.0f + expf(-x)); }

// ---------------- controller: wave-per-output ----------------
// grid (ceil(nout/4), B), block 256 = 4 waves. Output o = blockIdx.x*4 + wave.
// o in [0,64): k (tanh) + atomicAdd kv^2 into nk (nk pre-zeroed)
// o 64/65/66: beta / g / gamma;  o 67..69: raw s logits (softmax in address_kernel)
// o >= 70 (write phase only): write_all -> e sigmoided | a raw
__global__ __launch_bounds__(256) void controller_kernel(
    const float* __restrict__ hsrc,
    const float* __restrict__ kw, const float* __restrict__ kb,
    const float* __restrict__ cw, const float* __restrict__ cb,
    const float* __restrict__ sw, const float* __restrict__ sb,
    const float* __restrict__ ww, const float* __restrict__ wb,
    float* __restrict__ k_out, float* __restrict__ beta_o,
    float* __restrict__ g_o, float* __restrict__ gamma_o,
    float* __restrict__ nk_o, float* __restrict__ s_raw,
    float* __restrict__ wa_o, int nout)
{
    int b = blockIdx.y;
    int wave = threadIdx.x >> 6, lane = threadIdx.x & 63;
    int o = blockIdx.x * 4 + wave;
    if (o >= nout) return;
    const float* wrow; float bias;
    if (o < 64)      { wrow = kw + (size_t)o * H_;        bias = kb[o]; }
    else if (o < 67) { wrow = cw + (size_t)(o - 64) * H_; bias = cb[o - 64]; }
    else if (o < 70) { wrow = sw + (size_t)(o - 67) * H_; bias = sb[o - 67]; }
    else             { wrow = ww + (size_t)(o - 70) * H_; bias = wb[o - 70]; }
    const float* hb = hsrc + (size_t)b * H_;
    float acc = 0.0f;
    #pragma unroll
    for (int i = 0; i < 8; ++i) {
        int k = lane + i * 64;
        acc += hb[k] * wrow[k];
    }
    #pragma unroll
    for (int off = 32; off; off >>= 1) acc += __shfl_xor(acc, off);
    acc += bias;
    if (lane == 0) {
        if (o < 64) {
            float kv = tanhf(acc);
            k_out[b * M_ + o] = kv;
            atomicAdd(&nk_o[b], kv * kv);
        } else if (o == 64) {
            beta_o[b] = fmaxf(acc, 0.0f) + 1e-4f;
        } else if (o == 65) {
            g_o[b] = sigf(acc);
        } else if (o == 66) {
            gamma_o[b] = fmaxf(acc, 0.0f) + 1.0001f;
        } else if (o < 70) {
            s_raw[b * 3 + (o - 67)] = acc;
        } else {
            int j = o - 70;
            wa_o[b * 128 + j] = (j < 64) ? sigf(acc) : acc;
        }
    }
}

// ---------------- score pass: score[b,n] = beta * (k . M_bn) / (|M_bn|^2 * |k|^2) ----------------
// grid (32, B), block 256. 16 lanes cooperate per memory row (fully coalesced float4).
__global__ __launch_bounds__(256) void score_kernel(
    const float* __restrict__ mem, const float* __restrict__ kvec,
    const float* __restrict__ beta, const float* __restrict__ nk,
    float* __restrict__ score)
{
    int b = blockIdx.y;
    int lane = threadIdx.x & 63, wave = threadIdx.x >> 6;
    int mq = lane & 15, sub = lane >> 4;
    float4 k4 = ((const float4*)(kvec + b * M_))[mq];
    float be = beta[b], nkk = nk[b];
    const int chunk = N_ / 32;
    int base = blockIdx.x * chunk;
    const float4* memb = (const float4*)(mem + (size_t)b * N_ * M_);
    for (int it = 0; it < chunk / 16; ++it) {
        int n = base + it * 16 + wave * 4 + sub;
        float4 v = memb[(size_t)n * 16 + mq];
        float d  = v.x * k4.x + v.y * k4.y + v.z * k4.z + v.w * k4.w;
        float nm = v.x * v.x + v.y * v.y + v.z * v.z + v.w * v.w;
        #pragma unroll
        for (int off = 1; off < 16; off <<= 1) {
            d  += __shfl_xor(d, off);
            nm += __shfl_xor(nm, off);
        }
        if (mq == 0) score[(size_t)b * N_ + n] = be * d / (nm * nkk);
    }
}

// ---------------- address: softmax -> interpolate -> shift -> sharpen -> normalize ----------------
__global__ __launch_bounds__(1024) void address_kernel(
    const float* __restrict__ score, const float* __restrict__ head_tm1,
    const float* __restrict__ g_, const float* __restrict__ gamma_,
    const float* __restrict__ s_, float* __restrict__ head_out)
{
    int b = blockIdx.x;
    __shared__ float inter[N_];
    __shared__ float red[16];
    int tid = threadIdx.x;
    const float* sc = score + (size_t)b * N_;

    float v[8];
    float mx = -1e30f;
    #pragma unroll
    for (int r = 0; r < 8; ++r) { v[r] = sc[tid + r * 1024]; mx = fmaxf(mx, v[r]); }
    #pragma unroll
    for (int off = 32; off; off >>= 1) mx = fmaxf(mx, __shfl_xor(mx, off));
    if ((tid & 63) == 0) red[tid >> 6] = mx;
    __syncthreads();
    mx = red[0];
    for (int i = 1; i < 16; ++i) mx = fmaxf(mx, red[i]);
    __syncthreads();

    float sum = 0.0f;
    #pragma unroll
    for (int r = 0; r < 8; ++r) { v[r] = expf(v[r] - mx); sum += v[r]; }
    #pragma unroll
    for (int off = 32; off; off >>= 1) sum += __shfl_xor(sum, off);
    if ((tid & 63) == 0) red[tid >> 6] = sum;
    __syncthreads();
    sum = 0.0f;
    for (int i = 0; i < 16; ++i) sum += red[i];
    float inv = 1.0f / sum;
    __syncthreads();

    // 3-way softmax of raw shift logits
    float r0 = s_[b * 3], r1 = s_[b * 3 + 1], r2 = s_[b * 3 + 2];
    float mx3 = fmaxf(r0, fmaxf(r1, r2));
    float e0 = expf(r0 - mx3), e1 = expf(r1 - mx3), e2 = expf(r2 - mx3);
    float ss = e0 + e1 + e2;
    float s0 = e0 / ss, s1 = e1 / ss, s2 = e2 / ss;

    float gb = g_[b], gm = gamma_[b];
    const float* ht = head_tm1 + (size_t)b * N_;
    #pragma unroll
    for (int r = 0; r < 8; ++r) {
        int n = tid + r * 1024;
        inter[n] = gb * (v[r] * inv) + (1.0f - gb) * ht[n];
    }
    __syncthreads();

    float outv[8];
    float psum = 0.0f;
    #pragma unroll
    for (int r = 0; r < 8; ++r) {
        int n = tid + r * 1024;
        float o = s0 * inter[(n + N_ - 2) & (N_ - 1)]
                + s1 * inter[(n + N_ - 1) & (N_ - 1)]
                + s2 * inter[n];
        o = powf(fmaxf(o, 0.0f), gm);
        outv[r] = o;
        psum += o;
    }
    #pragma unroll
    for (int off = 32; off; off >>= 1) psum += __shfl_xor(psum, off);
    if ((tid & 63) == 0) red[tid >> 6] = psum;
    __syncthreads();
    psum = 0.0f;
    for (int i = 0; i < 16; ++i) psum += red[i];
    float inv2 = 1.0f / psum;
    float* ho = head_out + (size_t)b * N_;
    #pragma unroll
    for (int r = 0; r < 8; ++r) ho[tid + r * 1024] = outv[r] * inv2;
}

// ---------------- M_read[b,m] = sum_n r_head[b,n] * Mem[b,n,m] ----------------
// grid (32, B), block 256. Requires mread zeroed beforehand.
__global__ __launch_bounds__(256) void mread_kernel(
    const float* __restrict__ mem, const float* __restrict__ rhead,
    float* __restrict__ mread)
{
    int b = blockIdx.y;
    int lane = threadIdx.x & 63, wave = threadIdx.x >> 6;
    int mq = lane & 15, sub = lane >> 4;
    const int chunk = N_ / 32;
    int base = blockIdx.x * chunk;
    const float4* memb = (const float4*)(mem + (size_t)b * N_ * M_);
    const float* rh = rhead + (size_t)b * N_;
    float4 acc = make_float4(0.f, 0.f, 0.f, 0.f);
    for (int it = 0; it < chunk / 16; ++it) {
        int n = base + it * 16 + wave * 4 + sub;
        float w = rh[n];
        float4 v = memb[(size_t)n * 16 + mq];
        acc.x += w * v.x; acc.y += w * v.y; acc.z += w * v.z; acc.w += w * v.w;
    }
    #pragma unroll
    for (int off = 16; off < 64; off <<= 1) {
        acc.x += __shfl_xor(acc.x, off); acc.y += __shfl_xor(acc.y, off);
        acc.z += __shfl_xor(acc.z, off); acc.w += __shfl_xor(acc.w, off);
    }
    __shared__ float4 wsum[4][16];
    if (sub == 0) wsum[wave][mq] = acc;
    __syncthreads();
    if (threadIdx.x < 16) {
        float4 t = wsum[0][threadIdx.x];
        for (int w2 = 1; w2 < 4; ++w2) {
            float4 u = wsum[w2][threadIdx.x];
            t.x += u.x; t.y += u.y; t.z += u.z; t.w += u.w;
        }
        float* dst = mread + b * M_ + threadIdx.x * 4;
        atomicAdd(dst + 0, t.x); atomicAdd(dst + 1, t.y);
        atomicAdd(dst + 2, t.z); atomicAdd(dst + 3, t.w);
    }
}

// ---------------- gates = [inp|M_read] @ W_ih^T + b_ih + h @ W_hh^T + b_hh ----------------
// grid 256 blocks (8 j each), block 256 = 64 b x 4 waves; each wave owns 2 j rows.
__global__ __launch_bounds__(256) void gates_kernel(
    const float* __restrict__ inp, const float* __restrict__ mread,
    const float* __restrict__ h, const float* __restrict__ Wih,
    const float* __restrict__ bih, const float* __restrict__ Whh,
    const float* __restrict__ bhh, float* __restrict__ gates)
{
    int jb = blockIdx.x * 8;
    int tid = threadIdx.x;
    int bb = tid & 63;
    int jg = tid >> 6;           // wave id 0..3
    int j0 = jb + jg * 2;        // this wave's two output rows
    __shared__ float Xs[64][68];
    __shared__ float Ws[8][68];
    float acc0 = 0.f, acc1 = 0.f;

    for (int kb = 0; kb < 832; kb += 64) {
        for (int i = tid; i < 4096; i += 256) {
            int bl = i >> 6, kk = i & 63, k = kb + kk;
            float xv;
            if (k < IN_)            xv = inp[bl * IN_ + k];
            else if (k < IN_ + M_)  xv = mread[bl * M_ + (k - IN_)];
            else                    xv = h[bl * H_ + (k - IN_ - M_)];
            Xs[bl][kk] = xv;
        }
        for (int i = tid; i < 512; i += 256) {
            int jr = i >> 6, kk = i & 63, k = kb + kk;
            Ws[jr][kk] = (k < IN_ + M_)
                       ? Wih[(size_t)(jb + jr) * (IN_ + M_) + k]
                       : Whh[(size_t)(jb + jr) * H_ + (k - IN_ - M_)];
        }
        __syncthreads();
        #pragma unroll
        for (int kk = 0; kk < 64; kk += 4) {
            float4 x4 = *(const float4*)&Xs[bb][kk];
            float4 w0 = *(const float4*)&Ws[jg * 2 + 0][kk];
            float4 w1 = *(const float4*)&Ws[jg * 2 + 1][kk];
            acc0 += x4.x * w0.x + x4.y * w0.y + x4.z * w0.z + x4.w * w0.w;
            acc1 += x4.x * w1.x + x4.y * w1.y + x4.z * w1.z + x4.w * w1.w;
        }
        __syncthreads();
    }
    gates[bb * G4_ + j0]     = acc0 + bih[j0]     + bhh[j0];
    gates[bb * G4_ + j0 + 1] = acc1 + bih[j0 + 1] + bhh[j0 + 1];
}

// ---------------- LSTM pointwise ----------------
__global__ __launch_bounds__(256) void lstm_kernel(
    const float* __restrict__ gates, const float* __restrict__ c_in,
    float* __restrict__ h_new, float* __restrict__ c_new)
{
    int i = blockIdx.x * 256 + threadIdx.x;
    if (i >= B_ * H_) return;
    int b = i >> 9, hh = i & 511;
    const float* gb = gates + b * G4_;
    float ig = gb[hh], fg = gb[H_ + hh], gg = gb[2 * H_ + hh], og = gb[3 * H_ + hh];
    float cn = sigf(fg) * c_in[i] + sigf(ig) * tanhf(gg);
    float hn = sigf(og) * tanhf(cn);
    c_new[i] = cn;
    h_new[i] = hn;
}

// ---------------- M_out = mem * (1 - w*e) + w*a ----------------
__global__ __launch_bounds__(256) void writemem_kernel(
    const float* __restrict__ mem, const float* __restrict__ whead,
    const float* __restrict__ wa, float* __restrict__ mout)
{
    size_t i4 = (size_t)blockIdx.x * 256 + threadIdx.x;  // float4 index
    int mq = (int)(i4 & 15);
    int n  = (int)((i4 >> 4) & (N_ - 1));
    int b  = (int)(i4 >> 17);
    float w = whead[(size_t)b * N_ + n];
    float4 e4 = ((const float4*)(wa + b * 128))[mq];
    float4 a4 = ((const float4*)(wa + b * 128 + 64))[mq];
    float4 v = ((const float4*)mem)[i4];
    float4 o;
    o.x = v.x * (1.0f - w * e4.x) + w * a4.x;
    o.y = v.y * (1.0f - w * e4.y) + w * a4.y;
    o.z = v.z * (1.0f - w * e4.z) + w * a4.z;
    o.w = v.w * (1.0f - w * e4.w) + w * a4.w;
    ((float4*)mout)[i4] = o;
}

// ---------------- launch ----------------
extern "C" void kernel_launch(void* const* d_in, const int* in_sizes, int n_in,
                              void* d_out, int out_size, void* d_ws, size_t ws_size,
                              hipStream_t stream) {
    (void)in_sizes; (void)n_in; (void)out_size; (void)ws_size;
    const float* inp     = (const float*)d_in[0];
    const float* h       = (const float*)d_in[1];
    const float* c       = (const float*)d_in[2];
    const float* rhead0  = (const float*)d_in[3];
    const float* whead0  = (const float*)d_in[4];
    const float* mem     = (const float*)d_in[5];
    const float* W_ih    = (const float*)d_in[6];
    const float* b_ih    = (const float*)d_in[7];
    const float* W_hh    = (const float*)d_in[8];
    const float* b_hh    = (const float*)d_in[9];
    const float* rk_w    = (const float*)d_in[10];
    const float* rk_b    = (const float*)d_in[11];
    const float* rc_w    = (const float*)d_in[12];
    const float* rc_b    = (const float*)d_in[13];
    const float* rs_w    = (const float*)d_in[14];
    const float* rs_b    = (const float*)d_in[15];
    const float* wk_w    = (const float*)d_in[16];
    const float* wk_b    = (const float*)d_in[17];
    const float* wc_w    = (const float*)d_in[18];
    const float* wc_b    = (const float*)d_in[19];
    const float* ws_w    = (const float*)d_in[20];
    const float* ws_b    = (const float*)d_in[21];
    const float* w_w     = (const float*)d_in[22];
    const float* w_b     = (const float*)d_in[23];

    float* ws = (float*)d_ws;
    float* out = (float*)d_out;
    float* h_new  = out;                       // 32768
    float* c_new  = out + 32768;               // 32768
    float* r_head = out + 65536;               // 524288
    float* w_head = out + 65536 + 524288;      // 524288
    float* m_out  = out + 65536 + 2 * 524288;  // 33554432

    // zero M_read accumulator + both nk accumulators (contiguous region)
    hipMemsetAsync(ws + OFF_MREAD, 0, ZERO_FLTS * sizeof(float), stream);

    // ---- read phase ----
    controller_kernel<<<dim3(18, B_), 256, 0, stream>>>(
        h, rk_w, rk_b, rc_w, rc_b, rs_w, rs_b, w_w, w_b,
        ws + OFF_RK, ws + OFF_RBETA, ws + OFF_RG, ws + OFF_RGAMMA,
        ws + OFF_RNK, ws + OFF_RS, nullptr, 70);
    score_kernel<<<dim3(32, B_), 256, 0, stream>>>(
        mem, ws + OFF_RK, ws + OFF_RBETA, ws + OFF_RNK, ws + OFF_SCORE);
    address_kernel<<<B_, 1024, 0, stream>>>(
        ws + OFF_SCORE, rhead0, ws + OFF_RG, ws + OFF_RGAMMA, ws + OFF_RS, r_head);
    mread_kernel<<<dim3(32, B_), 256, 0, stream>>>(mem, r_head, ws + OFF_MREAD);

    // ---- LSTM ----
    gates_kernel<<<G4_ / 8, 256, 0, stream>>>(
        inp, ws + OFF_MREAD, h, W_ih, b_ih, W_hh, b_hh, ws + OFF_GATES);
    lstm_kernel<<<(B_ * H_ + 255) / 256, 256, 0, stream>>>(
        ws + OFF_GATES, c, h_new, c_new);

    // ---- write phase ----
    controller_kernel<<<dim3(50, B_), 256, 0, stream>>>(
        h_new, wk_w, wk_b, wc_w, wc_b, ws_w, ws_b, w_w, w_b,
        ws + OFF_WK, ws + OFF_WBETA, ws + OFF_WG, ws + OFF_WGAMMA,
        ws + OFF_WNK, ws + OFF_WS, ws + OFF_WA, 198);
    score_kernel<<<dim3(32, B_), 256, 0, stream>>>(
        mem, ws + OFF_WK, ws + OFF_WBETA, ws + OFF_WNK, ws + OFF_SCORE);
    address_kernel<<<B_, 1024, 0, stream>>>(
        ws + OFF_SCORE, whead0, ws + OFF_WG, ws + OFF_WGAMMA, ws + OFF_WS, w_head);
    writemem_kernel<<<(B_ * N_ * M_ / 4) / 256, 256, 0, stream>>>(
        mem, w_head, ws + OFF_WA, m_out);
}

// Round 9
// 492.067 us; speedup vs baseline: 1.0798x; 1.0257x over previous
//
#include <hip/hip_runtime.h>
#include <hip/hip_bf16.h>
#include <math.h>

#define B_ 64
#define IN_ 256
#define H_ 512
#define M_ 64
#define N_ 8192
#define G4_ 2048   // 4*H

// ---------------- workspace layout (float offsets) ----------------
#define OFF_SCORE  0          // B*N = 524288
#define OFF_GATES  524288     // B*4H = 131072
#define OFF_RK     655360     // 4096
#define OFF_WK     659456     // 4096
#define OFF_WA     663552     // B*128 = 8192 (e|a, e already sigmoided)
// ---- zeroed region (one memset covers MREAD..WNK) ----
#define OFF_MREAD  671744     // 4096
#define OFF_RNK    675840     // 64
#define OFF_WNK    675904     // 64
#define ZERO_FLTS  4224
// ---- scalars ----
#define OFF_RBETA  675968
#define OFF_RG     676032
#define OFF_RGAMMA 676096
#define OFF_RS     676160     // 192 (raw logits)
#define OFF_WBETA  676352
#define OFF_WG     676416
#define OFF_WGAMMA 676480
#define OFF_WS     676544     // 192 (raw logits)
// end ~ 676736 floats = 2.7 MB

__device__ __forceinline__ float sigf(float x) { return 1.0f / (1.0f + expf(-x)); }

// ---------------- controller: wave-per-output ----------------
// grid (ceil(nout/4), B), block 256 = 4 waves. Output o = blockIdx.x*4 + wave.
__global__ __launch_bounds__(256) void controller_kernel(
    const float* __restrict__ hsrc,
    const float* __restrict__ kw, const float* __restrict__ kb,
    const float* __restrict__ cw, const float* __restrict__ cb,
    const float* __restrict__ sw, const float* __restrict__ sb,
    const float* __restrict__ ww, const float* __restrict__ wb,
    float* __restrict__ k_out, float* __restrict__ beta_o,
    float* __restrict__ g_o, float* __restrict__ gamma_o,
    float* __restrict__ nk_o, float* __restrict__ s_raw,
    float* __restrict__ wa_o, int nout)
{
    int b = blockIdx.y;
    int wave = threadIdx.x >> 6, lane = threadIdx.x & 63;
    int o = blockIdx.x * 4 + wave;
    if (o >= nout) return;
    const float* wrow; float bias;
    if (o < 64)      { wrow = kw + (size_t)o * H_;        bias = kb[o]; }
    else if (o < 67) { wrow = cw + (size_t)(o - 64) * H_; bias = cb[o - 64]; }
    else if (o < 70) { wrow = sw + (size_t)(o - 67) * H_; bias = sb[o - 67]; }
    else             { wrow = ww + (size_t)(o - 70) * H_; bias = wb[o - 70]; }
    const float* hb = hsrc + (size_t)b * H_;
    float acc = 0.0f;
    #pragma unroll
    for (int i = 0; i < 8; ++i) {
        int k = lane + i * 64;
        acc += hb[k] * wrow[k];
    }
    #pragma unroll
    for (int off = 32; off; off >>= 1) acc += __shfl_xor(acc, off);
    acc += bias;
    if (lane == 0) {
        if (o < 64) {
            float kv = tanhf(acc);
            k_out[b * M_ + o] = kv;
            atomicAdd(&nk_o[b], kv * kv);
        } else if (o == 64) {
            beta_o[b] = fmaxf(acc, 0.0f) + 1e-4f;
        } else if (o == 65) {
            g_o[b] = sigf(acc);
        } else if (o == 66) {
            gamma_o[b] = fmaxf(acc, 0.0f) + 1.0001f;
        } else if (o < 70) {
            s_raw[b * 3 + (o - 67)] = acc;
        } else {
            int j = o - 70;
            wa_o[b * 128 + j] = (j < 64) ? sigf(acc) : acc;
        }
    }
}

// ---------------- score pass: score[b,n] = beta * (k . M_bn) / (|M_bn|^2 * |k|^2) ----------------
// grid (32, B), block 256. 16 lanes per memory row; 2-row unroll for MLP.
__global__ __launch_bounds__(256) void score_kernel(
    const float* __restrict__ mem, const float* __restrict__ kvec,
    const float* __restrict__ beta, const float* __restrict__ nk,
    float* __restrict__ score)
{
    int b = blockIdx.y;
    int lane = threadIdx.x & 63, wave = threadIdx.x >> 6;
    int mq = lane & 15, sub = lane >> 4;
    float4 k4 = ((const float4*)(kvec + b * M_))[mq];
    float be = beta[b], nkk = nk[b];
    const int chunk = N_ / 32;   // 256 rows per block
    int base = blockIdx.x * chunk;
    const float4* memb = (const float4*)(mem + (size_t)b * N_ * M_);
    for (int it = 0; it < chunk / 32; ++it) {
        int n0 = base + it * 32 + wave * 4 + sub;
        int n1 = n0 + 16;
        float4 v0 = memb[(size_t)n0 * 16 + mq];
        float4 v1 = memb[(size_t)n1 * 16 + mq];
        float d0  = v0.x * k4.x + v0.y * k4.y + v0.z * k4.z + v0.w * k4.w;
        float nm0 = v0.x * v0.x + v0.y * v0.y + v0.z * v0.z + v0.w * v0.w;
        float d1  = v1.x * k4.x + v1.y * k4.y + v1.z * k4.z + v1.w * k4.w;
        float nm1 = v1.x * v1.x + v1.y * v1.y + v1.z * v1.z + v1.w * v1.w;
        #pragma unroll
        for (int off = 1; off < 16; off <<= 1) {
            d0  += __shfl_xor(d0, off);  nm0 += __shfl_xor(nm0, off);
            d1  += __shfl_xor(d1, off);  nm1 += __shfl_xor(nm1, off);
        }
        if (mq == 0) {
            score[(size_t)b * N_ + n0] = be * d0 / (nm0 * nkk);
            score[(size_t)b * N_ + n1] = be * d1 / (nm1 * nkk);
        }
    }
}

// ---------------- address: softmax -> interpolate -> shift -> sharpen -> normalize ----------------
__global__ __launch_bounds__(1024) void address_kernel(
    const float* __restrict__ score, const float* __restrict__ head_tm1,
    const float* __restrict__ g_, const float* __restrict__ gamma_,
    const float* __restrict__ s_, float* __restrict__ head_out)
{
    int b = blockIdx.x;
    __shared__ float inter[N_];
    __shared__ float red[16];
    int tid = threadIdx.x;
    const float* sc = score + (size_t)b * N_;

    float v[8];
    float mx = -1e30f;
    #pragma unroll
    for (int r = 0; r < 8; ++r) { v[r] = sc[tid + r * 1024]; mx = fmaxf(mx, v[r]); }
    #pragma unroll
    for (int off = 32; off; off >>= 1) mx = fmaxf(mx, __shfl_xor(mx, off));
    if ((tid & 63) == 0) red[tid >> 6] = mx;
    __syncthreads();
    mx = red[0];
    for (int i = 1; i < 16; ++i) mx = fmaxf(mx, red[i]);
    __syncthreads();

    float sum = 0.0f;
    #pragma unroll
    for (int r = 0; r < 8; ++r) { v[r] = expf(v[r] - mx); sum += v[r]; }
    #pragma unroll
    for (int off = 32; off; off >>= 1) sum += __shfl_xor(sum, off);
    if ((tid & 63) == 0) red[tid >> 6] = sum;
    __syncthreads();
    sum = 0.0f;
    for (int i = 0; i < 16; ++i) sum += red[i];
    float inv = 1.0f / sum;
    __syncthreads();

    // 3-way softmax of raw shift logits
    float r0 = s_[b * 3], r1 = s_[b * 3 + 1], r2 = s_[b * 3 + 2];
    float mx3 = fmaxf(r0, fmaxf(r1, r2));
    float e0 = expf(r0 - mx3), e1 = expf(r1 - mx3), e2 = expf(r2 - mx3);
    float ss = e0 + e1 + e2;
    float s0 = e0 / ss, s1 = e1 / ss, s2 = e2 / ss;

    float gb = g_[b], gm = gamma_[b];
    const float* ht = head_tm1 + (size_t)b * N_;
    #pragma unroll
    for (int r = 0; r < 8; ++r) {
        int n = tid + r * 1024;
        inter[n] = gb * (v[r] * inv) + (1.0f - gb) * ht[n];
    }
    __syncthreads();

    float outv[8];
    float psum = 0.0f;
    #pragma unroll
    for (int r = 0; r < 8; ++r) {
        int n = tid + r * 1024;
        float o = s0 * inter[(n + N_ - 2) & (N_ - 1)]
                + s1 * inter[(n + N_ - 1) & (N_ - 1)]
                + s2 * inter[n];
        o = fmaxf(o, 0.0f);
        // o^gm via exp/log: o>=0; clamp keeps o==0 -> exp(gm*log(1e-30)) ~= 0
        o = __expf(gm * __logf(fmaxf(o, 1e-30f)));
        outv[r] = o;
        psum += o;
    }
    #pragma unroll
    for (int off = 32; off; off >>= 1) psum += __shfl_xor(psum, off);
    if ((tid & 63) == 0) red[tid >> 6] = psum;
    __syncthreads();
    psum = 0.0f;
    for (int i = 0; i < 16; ++i) psum += red[i];
    float inv2 = 1.0f / psum;
    float* ho = head_out + (size_t)b * N_;
    #pragma unroll
    for (int r = 0; r < 8; ++r) ho[tid + r * 1024] = outv[r] * inv2;
}

// ---------------- M_read[b,m] = sum_n r_head[b,n] * Mem[b,n,m] ----------------
// grid (32, B), block 256; 2-row unroll. Requires mread zeroed beforehand.
__global__ __launch_bounds__(256) void mread_kernel(
    const float* __restrict__ mem, const float* __restrict__ rhead,
    float* __restrict__ mread)
{
    int b = blockIdx.y;
    int lane = threadIdx.x & 63, wave = threadIdx.x >> 6;
    int mq = lane & 15, sub = lane >> 4;
    const int chunk = N_ / 32;
    int base = blockIdx.x * chunk;
    const float4* memb = (const float4*)(mem + (size_t)b * N_ * M_);
    const float* rh = rhead + (size_t)b * N_;
    float4 acc = make_float4(0.f, 0.f, 0.f, 0.f);
    for (int it = 0; it < chunk / 32; ++it) {
        int n0 = base + it * 32 + wave * 4 + sub;
        int n1 = n0 + 16;
        float w0 = rh[n0], w1 = rh[n1];
        float4 v0 = memb[(size_t)n0 * 16 + mq];
        float4 v1 = memb[(size_t)n1 * 16 + mq];
        acc.x += w0 * v0.x + w1 * v1.x;
        acc.y += w0 * v0.y + w1 * v1.y;
        acc.z += w0 * v0.z + w1 * v1.z;
        acc.w += w0 * v0.w + w1 * v1.w;
    }
    #pragma unroll
    for (int off = 16; off < 64; off <<= 1) {
        acc.x += __shfl_xor(acc.x, off); acc.y += __shfl_xor(acc.y, off);
        acc.z += __shfl_xor(acc.z, off); acc.w += __shfl_xor(acc.w, off);
    }
    __shared__ float4 wsum[4][16];
    if (sub == 0) wsum[wave][mq] = acc;
    __syncthreads();
    if (threadIdx.x < 16) {
        float4 t = wsum[0][threadIdx.x];
        for (int w2 = 1; w2 < 4; ++w2) {
            float4 u = wsum[w2][threadIdx.x];
            t.x += u.x; t.y += u.y; t.z += u.z; t.w += u.w;
        }
        float* dst = mread + b * M_ + threadIdx.x * 4;
        atomicAdd(dst + 0, t.x); atomicAdd(dst + 1, t.y);
        atomicAdd(dst + 2, t.z); atomicAdd(dst + 3, t.w);
    }
}

// ---------------- gates = [inp|M_read] @ W_ih^T + b_ih + h @ W_hh^T + b_hh ----------------
// grid 256 blocks (8 j each), block 256 = 64 b x 4 waves; each wave owns 2 j rows.
__global__ __launch_bounds__(256) void gates_kernel(
    const float* __restrict__ inp, const float* __restrict__ mread,
    const float* __restrict__ h, const float* __restrict__ Wih,
    const float* __restrict__ bih, const float* __restrict__ Whh,
    const float* __restrict__ bhh, float* __restrict__ gates)
{
    int jb = blockIdx.x * 8;
    int tid = threadIdx.x;
    int bb = tid & 63;
    int jg = tid >> 6;           // wave id 0..3
    int j0 = jb + jg * 2;        // this wave's two output rows
    __shared__ float Xs[64][68];
    __shared__ float Ws[8][68];
    float acc0 = 0.f, acc1 = 0.f;

    for (int kb = 0; kb < 832; kb += 64) {
        for (int i = tid; i < 4096; i += 256) {
            int bl = i >> 6, kk = i & 63, k = kb + kk;
            float xv;
            if (k < IN_)            xv = inp[bl * IN_ + k];
            else if (k < IN_ + M_)  xv = mread[bl * M_ + (k - IN_)];
            else                    xv = h[bl * H_ + (k - IN_ - M_)];
            Xs[bl][kk] = xv;
        }
        for (int i = tid; i < 512; i += 256) {
            int jr = i >> 6, kk = i & 63, k = kb + kk;
            Ws[jr][kk] = (k < IN_ + M_)
                       ? Wih[(size_t)(jb + jr) * (IN_ + M_) + k]
                       : Whh[(size_t)(jb + jr) * H_ + (k - IN_ - M_)];
        }
        __syncthreads();
        #pragma unroll
        for (int kk = 0; kk < 64; kk += 4) {
            float4 x4 = *(const float4*)&Xs[bb][kk];
            float4 w0 = *(const float4*)&Ws[jg * 2 + 0][kk];
            float4 w1 = *(const float4*)&Ws[jg * 2 + 1][kk];
            acc0 += x4.x * w0.x + x4.y * w0.y + x4.z * w0.z + x4.w * w0.w;
            acc1 += x4.x * w1.x + x4.y * w1.y + x4.z * w1.z + x4.w * w1.w;
        }
        __syncthreads();
    }
    gates[bb * G4_ + j0]     = acc0 + bih[j0]     + bhh[j0];
    gates[bb * G4_ + j0 + 1] = acc1 + bih[j0 + 1] + bhh[j0 + 1];
}

// ---------------- LSTM pointwise ----------------
__global__ __launch_bounds__(256) void lstm_kernel(
    const float* __restrict__ gates, const float* __restrict__ c_in,
    float* __restrict__ h_new, float* __restrict__ c_new)
{
    int i = blockIdx.x * 256 + threadIdx.x;
    if (i >= B_ * H_) return;
    int b = i >> 9, hh = i & 511;
    const float* gb = gates + b * G4_;
    float ig = gb[hh], fg = gb[H_ + hh], gg = gb[2 * H_ + hh], og = gb[3 * H_ + hh];
    float cn = sigf(fg) * c_in[i] + sigf(ig) * tanhf(gg);
    float hn = sigf(og) * tanhf(cn);
    c_new[i] = cn;
    h_new[i] = hn;
}

// ---------------- M_out = mem * (1 - w*e) + w*a ----------------
__global__ __launch_bounds__(256) void writemem_kernel(
    const float* __restrict__ mem, const float* __restrict__ whead,
    const float* __restrict__ wa, float* __restrict__ mout)
{
    size_t i4 = (size_t)blockIdx.x * 256 + threadIdx.x;  // float4 index
    int mq = (int)(i4 & 15);
    int n  = (int)((i4 >> 4) & (N_ - 1));
    int b  = (int)(i4 >> 17);
    float w = whead[(size_t)b * N_ + n];
    float4 e4 = ((const float4*)(wa + b * 128))[mq];
    float4 a4 = ((const float4*)(wa + b * 128 + 64))[mq];
    float4 v = ((const float4*)mem)[i4];
    float4 o;
    o.x = v.x * (1.0f - w * e4.x) + w * a4.x;
    o.y = v.y * (1.0f - w * e4.y) + w * a4.y;
    o.z = v.z * (1.0f - w * e4.z) + w * a4.z;
    o.w = v.w * (1.0f - w * e4.w) + w * a4.w;
    ((float4*)mout)[i4] = o;
}

// ---------------- launch ----------------
extern "C" void kernel_launch(void* const* d_in, const int* in_sizes, int n_in,
                              void* d_out, int out_size, void* d_ws, size_t ws_size,
                              hipStream_t stream) {
    (void)in_sizes; (void)n_in; (void)out_size; (void)ws_size;
    const float* inp     = (const float*)d_in[0];
    const float* h       = (const float*)d_in[1];
    const float* c       = (const float*)d_in[2];
    const float* rhead0  = (const float*)d_in[3];
    const float* whead0  = (const float*)d_in[4];
    const float* mem     = (const float*)d_in[5];
    const float* W_ih    = (const float*)d_in[6];
    const float* b_ih    = (const float*)d_in[7];
    const float* W_hh    = (const float*)d_in[8];
    const float* b_hh    = (const float*)d_in[9];
    const float* rk_w    = (const float*)d_in[10];
    const float* rk_b    = (const float*)d_in[11];
    const float* rc_w    = (const float*)d_in[12];
    const float* rc_b    = (const float*)d_in[13];
    const float* rs_w    = (const float*)d_in[14];
    const float* rs_b    = (const float*)d_in[15];
    const float* wk_w    = (const float*)d_in[16];
    const float* wk_b    = (const float*)d_in[17];
    const float* wc_w    = (const float*)d_in[18];
    const float* wc_b    = (const float*)d_in[19];
    const float* ws_w    = (const float*)d_in[20];
    const float* ws_b    = (const float*)d_in[21];
    const float* w_w     = (const float*)d_in[22];
    const float* w_b     = (const float*)d_in[23];

    float* ws = (float*)d_ws;
    float* out = (float*)d_out;
    float* h_new  = out;                       // 32768
    float* c_new  = out + 32768;               // 32768
    float* r_head = out + 65536;               // 524288
    float* w_head = out + 65536 + 524288;      // 524288
    float* m_out  = out + 65536 + 2 * 524288;  // 33554432

    // zero M_read accumulator + both nk accumulators (contiguous region)
    hipMemsetAsync(ws + OFF_MREAD, 0, ZERO_FLTS * sizeof(float), stream);

    // ---- read phase ----
    controller_kernel<<<dim3(18, B_), 256, 0, stream>>>(
        h, rk_w, rk_b, rc_w, rc_b, rs_w, rs_b, w_w, w_b,
        ws + OFF_RK, ws + OFF_RBETA, ws + OFF_RG, ws + OFF_RGAMMA,
        ws + OFF_RNK, ws + OFF_RS, nullptr, 70);
    score_kernel<<<dim3(32, B_), 256, 0, stream>>>(
        mem, ws + OFF_RK, ws + OFF_RBETA, ws + OFF_RNK, ws + OFF_SCORE);
    address_kernel<<<B_, 1024, 0, stream>>>(
        ws + OFF_SCORE, rhead0, ws + OFF_RG, ws + OFF_RGAMMA, ws + OFF_RS, r_head);
    mread_kernel<<<dim3(32, B_), 256, 0, stream>>>(mem, r_head, ws + OFF_MREAD);

    // ---- LSTM ----
    gates_kernel<<<G4_ / 8, 256, 0, stream>>>(
        inp, ws + OFF_MREAD, h, W_ih, b_ih, W_hh, b_hh, ws + OFF_GATES);
    lstm_kernel<<<(B_ * H_ + 255) / 256, 256, 0, stream>>>(
        ws + OFF_GATES, c, h_new, c_new);

    // ---- write phase ----
    controller_kernel<<<dim3(50, B_), 256, 0, stream>>>(
        h_new, wk_w, wk_b, wc_w, wc_b, ws_w, ws_b, w_w, w_b,
        ws + OFF_WK, ws + OFF_WBETA, ws + OFF_WG, ws + OFF_WGAMMA,
        ws + OFF_WNK, ws + OFF_WS, ws + OFF_WA, 198);
    score_kernel<<<dim3(32, B_), 256, 0, stream>>>(
        mem, ws + OFF_WK, ws + OFF_WBETA, ws + OFF_WNK, ws + OFF_SCORE);
    address_kernel<<<B_, 1024, 0, stream>>>(
        ws + OFF_SCORE, whead0, ws + OFF_WG, ws + OFF_WGAMMA, ws + OFF_WS, w_head);
    writemem_kernel<<<(B_ * N_ * M_ / 4) / 256, 256, 0, stream>>>(
        mem, w_head, ws + OFF_WA, m_out);
}